// Round 3
// baseline (171.603 us; speedup 1.0000x reference)
//
#include <hip/hip_runtime.h>
#include <hip/hip_bf16.h>
#include <stdint.h>

typedef unsigned short u16;
typedef unsigned int u32;
typedef __attribute__((ext_vector_type(8))) short short8;
typedef __attribute__((ext_vector_type(4))) float float4v;

#define CH 128
#define OO 128
#define KD 1152      // 9*128
#define MPIX 32768   // 8*64*64
#define LDA 72       // padded LDS row stride (u16): 64 data + 8 pad -> bank-spread, 16B-aligned rows

__device__ __forceinline__ u16 f2bf(float v) {
    __hip_bfloat16 h = __float2bfloat16(v);
    return *reinterpret_cast<u16*>(&h);
}
__device__ __forceinline__ float bf_lo(u32 u) { u32 t = u << 16;        return __builtin_bit_cast(float, t); }
__device__ __forceinline__ float bf_hi(u32 u) { u32 t = u & 0xffff0000u; return __builtin_bit_cast(float, t); }
__device__ __forceinline__ u32 pack_bf16(float lo, float hi) {
    u32 ul = __builtin_bit_cast(u32, lo);
    u32 uh = __builtin_bit_cast(u32, hi);
    return ((ul + 0x8000u) >> 16) | ((uh + 0x8000u) & 0xffff0000u);
}

// ---------------- transpose x (B,C,H,W) f32 -> xt (B,H,W,C) bf16 ----------------
__global__ __launch_bounds__(256) void transpose_kernel(const float* __restrict__ x,
                                                        __hip_bfloat16* __restrict__ xt) {
    __shared__ float st[64][65];
    int tid = threadIdx.x;
    int bh = blockIdx.x;              // b*64 + h
    int b = bh >> 6;
    int h = bh & 63;
    const float* xb = x + ((size_t)b * CH) * 4096 + (size_t)h * 64;
    __hip_bfloat16* xo = xt + ((size_t)bh << 6) * CH;
    for (int cc0 = 0; cc0 < 128; cc0 += 64) {
        #pragma unroll
        for (int step = 0; step < 16; ++step) {
            int cl = (tid >> 6) + step * 4;
            int w = tid & 63;
            st[cl][w] = xb[(size_t)(cc0 + cl) * 4096 + w];
        }
        __syncthreads();
        #pragma unroll
        for (int step = 0; step < 16; ++step) {
            int w = (tid >> 6) + step * 4;
            int cl = tid & 63;
            xo[(size_t)w * CH + cc0 + cl] = __float2bfloat16(st[cl][w]);
        }
        __syncthreads();
    }
}

// ---------------- offset conv: only the 6 needed channels, 4-way c-split ----------------
__global__ __launch_bounds__(256) void offset_conv_kernel(const float* __restrict__ x,
                                                          const float* __restrict__ w_off,
                                                          float* __restrict__ partial) {
    int tid = threadIdx.x;
    int m = blockIdx.x * 256 + tid;
    int chunk = blockIdx.y;           // 0..3, 32 channels each
    int b = m >> 12;
    int hw = m & 4095;
    int h = hw >> 6;
    int w = hw & 63;
    float acc[6] = {0.f, 0.f, 0.f, 0.f, 0.f, 0.f};
    int c0 = chunk * 32;
    for (int c = c0; c < c0 + 32; ++c) {
        const float* xc = x + ((size_t)(b * CH + c) << 12);
        float xv[9];
        #pragma unroll
        for (int dy = 0; dy < 3; ++dy) {
            int yy = h + dy - 1;
            bool vy = (unsigned)yy < 64u;
            #pragma unroll
            for (int dx = 0; dx < 3; ++dx) {
                int xx = w + dx - 1;
                bool vv = vy && ((unsigned)xx < 64u);
                xv[dy * 3 + dx] = vv ? xc[yy * 64 + xx] : 0.f;
            }
        }
        const float* wb = w_off + (size_t)c * 9;
        #pragma unroll
        for (int s = 0; s < 6; ++s) {
            int chn = (s < 3) ? s * 6 : (s - 3) * 2 + 1;
            const float* wp = wb + (size_t)chn * (CH * 9);
            float a = acc[s];
            #pragma unroll
            for (int t = 0; t < 9; ++t) a = fmaf(xv[t], wp[t], a);
            acc[s] = a;
        }
    }
    float* po = partial + ((size_t)(chunk << 15) + m) * 6;
    #pragma unroll
    for (int s = 0; s < 6; ++s) po[s] = acc[s];
}

// ---------------- reorder w_main (O,C,3,3) f32 -> Wb[o][k*128+c] bf16 ----------------
__global__ __launch_bounds__(256) void wreorder_kernel(const float* __restrict__ w_main,
                                                       u16* __restrict__ Wb) {
    int idx = blockIdx.x * 256 + threadIdx.x;
    if (idx >= OO * KD) return;
    int o = idx / KD;
    int r = idx - o * KD;
    int k = r >> 7;
    int c = r & 127;
    Wb[idx] = f2bf(w_main[(size_t)o * KD + c * 9 + k]);
}

// ---------------- fused deformable-sample + GEMM ----------------
// One block per 128-pixel tile; o tile = full 128. K-loop: 18 half-steps of 64 kc.
// LDS: lA 128x72 u16 (Wb slice), lB 128x72 u16 (sampled slice), gxy 1152 float2.
__global__ __launch_bounds__(256) void fused_gemm_kernel(const __hip_bfloat16* __restrict__ xt,
                                                         const float* __restrict__ partial,
                                                         const float* __restrict__ b_off,
                                                         const u16* __restrict__ Wb,
                                                         const float* __restrict__ b_main,
                                                         float* __restrict__ out) {
    __shared__ __align__(16) u16 lA[128 * LDA];
    __shared__ __align__(16) u16 lB[128 * LDA];
    __shared__ float2 gxy[128 * 9];

    int tid = threadIdx.x;
    int wave = tid >> 6;
    int lane = tid & 63;
    int wm = wave & 1;                 // o half (64)
    int wn = wave >> 1;                // pixel half (64)
    int mrow = lane & 15;
    int q8 = (lane >> 4) * 8;
    int pb = blockIdx.x * 128;         // pixel tile base (within one image: 128 | 4096)
    int bimg = pb >> 12;

    // ---- preamble 1: per-pixel offsets (6 values) into lB-aliased scratch ----
    float* offs = (float*)lB;          // 128*6 floats = 3 KB, overwritten by k-loop later
    for (int idx = tid; idx < 128 * 6; idx += 256) {
        int px = idx / 6, s = idx - px * 6;
        int m = pb + px;
        int chn = (s < 3) ? s * 6 : (s - 3) * 2 + 1;
        float v = b_off[chn];
        #pragma unroll
        for (int q = 0; q < 4; ++q) v += partial[((size_t)(q << 15) + m) * 6 + s];
        offs[idx] = v;
    }
    __syncthreads();
    // ---- preamble 2: sample coords gxy[px][k] ----
    for (int idx = tid; idx < 128 * 9; idx += 256) {
        int px = idx / 9, k = idx - px * 9;
        int i = k / 3, j = k - i * 3;
        float ox = offs[px * 6 + 0];
        if (i >= 1) ox += offs[px * 6 + 1];
        if (i >= 2) ox += offs[px * 6 + 2];
        float oy = offs[px * 6 + 3];
        if (j >= 1) oy += offs[px * 6 + 4];
        if (j >= 2) oy += offs[px * 6 + 5];
        int m = pb + px;
        int h = (m & 4095) >> 6;
        int w = m & 63;
        const float step = 2.0f / 63.0f;
        float bxn = -1.0f + w * step;
        float byn = -1.0f + h * step;
        gxy[idx] = make_float2(fmaf(bxn + ox, 32.0f, 31.5f),
                               fmaf(byn + oy, 32.0f, 31.5f));
    }
    __syncthreads();

    float4v acc[4][4];
    #pragma unroll
    for (int sm = 0; sm < 4; ++sm)
        #pragma unroll
        for (int sn = 0; sn < 4; ++sn)
            acc[sm][sn] = (float4v){0.f, 0.f, 0.f, 0.f};

    const u32* xb = (const u32*)(xt + (((size_t)bimg << 12) * CH));  // bf16 pairs

    for (int ks = 0; ks < 18; ++ks) {
        int k = ks >> 1;
        int chalf = ks & 1;
        // ---- stage A: Wb[o][k*128 + chalf*64 + 0..64) -> lA, 4 uint4/thread ----
        #pragma unroll
        for (int q = 0; q < 4; ++q) {
            int unit = q * 256 + tid;
            int o = unit >> 3, cg = unit & 7;
            *(uint4*)&lA[o * LDA + cg * 8] =
                *(const uint4*)(Wb + (size_t)o * KD + k * 128 + chalf * 64 + cg * 8);
        }
        // ---- stage B: bilinear-sample 128px x 64c -> lB, 4 units/thread ----
        #pragma unroll
        for (int q = 0; q < 4; ++q) {
            int unit = q * 256 + tid;
            int px = unit >> 3, cg = unit & 7;
            int c8 = chalf * 64 + cg * 8;
            float2 g = gxy[px * 9 + k];
            float x0f = floorf(g.x), y0f = floorf(g.y);
            float wx = g.x - x0f, wy = g.y - y0f;
            int ix0 = (int)x0f, iy0 = (int)y0f;
            int ix1 = ix0 + 1, iy1 = iy0 + 1;
            float fx0 = ((unsigned)ix0 < 64u) ? 1.f : 0.f;
            float fx1 = ((unsigned)ix1 < 64u) ? 1.f : 0.f;
            float fy0 = ((unsigned)iy0 < 64u) ? 1.f : 0.f;
            float fy1 = ((unsigned)iy1 < 64u) ? 1.f : 0.f;
            float w00 = (1.f - wy) * (1.f - wx) * fy0 * fx0;
            float w01 = (1.f - wy) * wx * fy0 * fx1;
            float w10 = wy * (1.f - wx) * fy1 * fx0;
            float w11 = wy * wx * fy1 * fx1;
            int cx0 = min(max(ix0, 0), 63), cx1 = min(max(ix1, 0), 63);
            int cy0 = min(max(iy0, 0), 63), cy1 = min(max(iy1, 0), 63);
            int base00 = ((cy0 * 64 + cx0) * CH + c8) >> 1;
            int base01 = ((cy0 * 64 + cx1) * CH + c8) >> 1;
            int base10 = ((cy1 * 64 + cx0) * CH + c8) >> 1;
            int base11 = ((cy1 * 64 + cx1) * CH + c8) >> 1;
            uint4 u00 = *(const uint4*)(xb + base00);
            uint4 u01 = *(const uint4*)(xb + base01);
            uint4 u10 = *(const uint4*)(xb + base10);
            uint4 u11 = *(const uint4*)(xb + base11);
            const u32* p00 = (const u32*)&u00;
            const u32* p01 = (const u32*)&u01;
            const u32* p10 = (const u32*)&u10;
            const u32* p11 = (const u32*)&u11;
            u32 outp[4];
            #pragma unroll
            for (int qq = 0; qq < 4; ++qq) {
                float lo = w00 * bf_lo(p00[qq]);
                lo = fmaf(w01, bf_lo(p01[qq]), lo);
                lo = fmaf(w10, bf_lo(p10[qq]), lo);
                lo = fmaf(w11, bf_lo(p11[qq]), lo);
                float hi = w00 * bf_hi(p00[qq]);
                hi = fmaf(w01, bf_hi(p01[qq]), hi);
                hi = fmaf(w10, bf_hi(p10[qq]), hi);
                hi = fmaf(w11, bf_hi(p11[qq]), hi);
                outp[qq] = pack_bf16(lo, hi);
            }
            *(uint4*)&lB[px * LDA + cg * 8] = *(const uint4*)outp;
        }
        __syncthreads();
        // ---- MFMA over the 64-kc slice (2 substeps of 32) ----
        #pragma unroll
        for (int s = 0; s < 2; ++s) {
            short8 af[4], bfv[4];
            #pragma unroll
            for (int sm = 0; sm < 4; ++sm)
                af[sm] = *(const short8*)&lA[(wm * 64 + sm * 16 + mrow) * LDA + s * 32 + q8];
            #pragma unroll
            for (int sn = 0; sn < 4; ++sn)
                bfv[sn] = *(const short8*)&lB[(wn * 64 + sn * 16 + mrow) * LDA + s * 32 + q8];
            #pragma unroll
            for (int sm = 0; sm < 4; ++sm)
                #pragma unroll
                for (int sn = 0; sn < 4; ++sn)
                    acc[sm][sn] = __builtin_amdgcn_mfma_f32_16x16x32_bf16(af[sm], bfv[sn],
                                                                         acc[sm][sn], 0, 0, 0);
        }
        __syncthreads();
    }

    // ---- epilogue: C/D layout col=lane&15 (pixel), row=(lane>>4)*4+r (o) ----
    #pragma unroll
    for (int sm = 0; sm < 4; ++sm) {
        int o = wm * 64 + sm * 16 + (lane >> 4) * 4;
        #pragma unroll
        for (int sn = 0; sn < 4; ++sn) {
            int pcol = pb + wn * 64 + sn * 16 + mrow;
            int b = pcol >> 12;
            int rem = pcol & 4095;
            float* op = out + (((size_t)b * OO) << 12) + rem;
            #pragma unroll
            for (int r = 0; r < 4; ++r)
                op[(size_t)(o + r) << 12] = acc[sm][sn][r] + b_main[o + r];
        }
    }
}

extern "C" void kernel_launch(void* const* d_in, const int* in_sizes, int n_in,
                              void* d_out, int out_size, void* d_ws, size_t ws_size,
                              hipStream_t stream) {
    const float* x      = (const float*)d_in[0];
    const float* w_off  = (const float*)d_in[1];
    const float* b_off  = (const float*)d_in[2];
    const float* w_main = (const float*)d_in[3];
    const float* b_main = (const float*)d_in[4];
    float* out = (float*)d_out;

    char* ws = (char*)d_ws;
    __hip_bfloat16* xt = (__hip_bfloat16*)ws;                         // 8 MB
    float* partial = (float*)(ws + 8388608);                          // 3 MB
    u16* Wb   = (u16*)(ws + 8388608 + 3145728);                       // 288 KB

    transpose_kernel<<<512, 256, 0, stream>>>(x, xt);
    offset_conv_kernel<<<dim3(128, 4), 256, 0, stream>>>(x, w_off, partial);
    wreorder_kernel<<<576, 256, 0, stream>>>(w_main, Wb);
    fused_gemm_kernel<<<256, 256, 0, stream>>>(xt, partial, b_off, Wb, b_main, out);
}

// Round 4
// 143.518 us; speedup vs baseline: 1.1957x; 1.1957x over previous
//
#include <hip/hip_runtime.h>
#include <hip/hip_bf16.h>
#include <stdint.h>

typedef unsigned short u16;
typedef unsigned int u32;
typedef __attribute__((ext_vector_type(8))) short short8;
typedef __attribute__((ext_vector_type(4))) float float4v;

#define CH 128
#define OO 128
#define KD 1152      // 9*128
#define PXT 32       // pixels per fused block
#define LDB 72       // lB row stride in u16 (64 data + 8 pad)

__device__ __forceinline__ u16 f2bf(float v) {
    __hip_bfloat16 h = __float2bfloat16(v);
    return *reinterpret_cast<u16*>(&h);
}
__device__ __forceinline__ float bf_lo(u32 u) { u32 t = u << 16;         return __builtin_bit_cast(float, t); }
__device__ __forceinline__ float bf_hi(u32 u) { u32 t = u & 0xffff0000u; return __builtin_bit_cast(float, t); }
__device__ __forceinline__ u32 pack_bf16(float lo, float hi) {
    u32 ul = __builtin_bit_cast(u32, lo);
    u32 uh = __builtin_bit_cast(u32, hi);
    return ((ul + 0x8000u) >> 16) | ((uh + 0x8000u) & 0xffff0000u);
}

// bilinear-sample 8 consecutive channels at (g.x,g.y), zero-pad OOB, pack to bf16x8
__device__ __forceinline__ uint4 sample8(const u32* __restrict__ xb, float2 g, int c8) {
    float x0f = floorf(g.x), y0f = floorf(g.y);
    float wx = g.x - x0f, wy = g.y - y0f;
    int ix0 = (int)x0f, iy0 = (int)y0f;
    int ix1 = ix0 + 1, iy1 = iy0 + 1;
    float fx0 = ((unsigned)ix0 < 64u) ? 1.f : 0.f;
    float fx1 = ((unsigned)ix1 < 64u) ? 1.f : 0.f;
    float fy0 = ((unsigned)iy0 < 64u) ? 1.f : 0.f;
    float fy1 = ((unsigned)iy1 < 64u) ? 1.f : 0.f;
    float w00 = (1.f - wy) * (1.f - wx) * fy0 * fx0;
    float w01 = (1.f - wy) * wx * fy0 * fx1;
    float w10 = wy * (1.f - wx) * fy1 * fx0;
    float w11 = wy * wx * fy1 * fx1;
    int cx0 = min(max(ix0, 0), 63), cx1 = min(max(ix1, 0), 63);
    int cy0 = min(max(iy0, 0), 63), cy1 = min(max(iy1, 0), 63);
    uint4 u00 = *(const uint4*)(xb + (((cy0 * 64 + cx0) * CH + c8) >> 1));
    uint4 u01 = *(const uint4*)(xb + (((cy0 * 64 + cx1) * CH + c8) >> 1));
    uint4 u10 = *(const uint4*)(xb + (((cy1 * 64 + cx0) * CH + c8) >> 1));
    uint4 u11 = *(const uint4*)(xb + (((cy1 * 64 + cx1) * CH + c8) >> 1));
    const u32* p00 = (const u32*)&u00;
    const u32* p01 = (const u32*)&u01;
    const u32* p10 = (const u32*)&u10;
    const u32* p11 = (const u32*)&u11;
    uint4 r;
    u32* pr = (u32*)&r;
    #pragma unroll
    for (int qq = 0; qq < 4; ++qq) {
        float lo = w00 * bf_lo(p00[qq]);
        lo = fmaf(w01, bf_lo(p01[qq]), lo);
        lo = fmaf(w10, bf_lo(p10[qq]), lo);
        lo = fmaf(w11, bf_lo(p11[qq]), lo);
        float hi = w00 * bf_hi(p00[qq]);
        hi = fmaf(w01, bf_hi(p01[qq]), hi);
        hi = fmaf(w10, bf_hi(p10[qq]), hi);
        hi = fmaf(w11, bf_hi(p11[qq]), hi);
        pr[qq] = pack_bf16(lo, hi);
    }
    return r;
}

// ---------------- prep: transpose (bid<512) | offset conv (512..1023) | wreorder (1024..1599) ----
__global__ __launch_bounds__(256) void prep_kernel(const float* __restrict__ x,
                                                   const float* __restrict__ w_off,
                                                   const float* __restrict__ w_main,
                                                   __hip_bfloat16* __restrict__ xt,
                                                   float* __restrict__ partial,
                                                   u16* __restrict__ Wb) {
    __shared__ float st[64][65];
    int bid = blockIdx.x;
    int tid = threadIdx.x;
    if (bid < 512) {
        // transpose x (B,C,H,W) f32 -> xt (B,H,W,C) bf16
        int b = bid >> 6;
        int h = bid & 63;
        const float* xb = x + ((size_t)b * CH) * 4096 + (size_t)h * 64;
        __hip_bfloat16* xo = xt + ((size_t)bid << 6) * CH;
        for (int cc0 = 0; cc0 < 128; cc0 += 64) {
            #pragma unroll
            for (int step = 0; step < 16; ++step) {
                int cl = (tid >> 6) + step * 4;
                int w = tid & 63;
                st[cl][w] = xb[(size_t)(cc0 + cl) * 4096 + w];
            }
            __syncthreads();
            #pragma unroll
            for (int step = 0; step < 16; ++step) {
                int w = (tid >> 6) + step * 4;
                int cl = tid & 63;
                xo[(size_t)w * CH + cc0 + cl] = __float2bfloat16(st[cl][w]);
            }
            __syncthreads();
        }
    } else if (bid < 1024) {
        // offset conv: only the 6 needed channels, 4-way c-split
        int mb = (bid - 512) & 127;
        int chunk = (bid - 512) >> 7;
        int m = mb * 256 + tid;
        int b = m >> 12;
        int hw = m & 4095;
        int h = hw >> 6;
        int w = hw & 63;
        float acc[6] = {0.f, 0.f, 0.f, 0.f, 0.f, 0.f};
        int c0 = chunk * 32;
        for (int c = c0; c < c0 + 32; ++c) {
            const float* xc = x + ((size_t)(b * CH + c) << 12);
            float xv[9];
            #pragma unroll
            for (int dy = 0; dy < 3; ++dy) {
                int yy = h + dy - 1;
                bool vy = (unsigned)yy < 64u;
                #pragma unroll
                for (int dx = 0; dx < 3; ++dx) {
                    int xx = w + dx - 1;
                    bool vv = vy && ((unsigned)xx < 64u);
                    xv[dy * 3 + dx] = vv ? xc[yy * 64 + xx] : 0.f;
                }
            }
            const float* wbp = w_off + (size_t)c * 9;
            #pragma unroll
            for (int s = 0; s < 6; ++s) {
                int chn = (s < 3) ? s * 6 : (s - 3) * 2 + 1;
                const float* wp = wbp + (size_t)chn * (CH * 9);
                float a = acc[s];
                #pragma unroll
                for (int t = 0; t < 9; ++t) a = fmaf(xv[t], wp[t], a);
                acc[s] = a;
            }
        }
        float* po = partial + ((size_t)(chunk << 15) + m) * 6;
        #pragma unroll
        for (int s = 0; s < 6; ++s) po[s] = acc[s];
    } else {
        // reorder w_main (O,C,3,3) f32 -> Wb[o][k*128+c] bf16
        int idx = (bid - 1024) * 256 + tid;
        if (idx < OO * KD) {
            int o = idx / KD;
            int r = idx - o * KD;
            int k = r >> 7;
            int c = r & 127;
            Wb[idx] = f2bf(w_main[(size_t)o * KD + c * 9 + k]);
        }
    }
}

// ---------------- fused deformable-sample + GEMM v2 ----------------
// 32 pixels x 128 o per block, grid 1024 (4 blocks/CU). A (Wb) direct global->reg
// fragments (L2-resident). B sampled into double-buffered LDS, 1 barrier/step.
__global__ __launch_bounds__(256, 4) void fused_gemm_kernel(const __hip_bfloat16* __restrict__ xt,
                                                            const float* __restrict__ partial,
                                                            const float* __restrict__ b_off,
                                                            const u16* __restrict__ Wb,
                                                            const float* __restrict__ b_main,
                                                            float* __restrict__ out) {
    __shared__ __align__(16) u16 lB[2][PXT * LDB];   // 2 x 4608 B
    __shared__ float2 gxy[PXT * 9];                  // 2304 B
    __shared__ float offs[PXT * 6];                  // 768 B

    int tid = threadIdx.x;
    int wave = tid >> 6;
    int lane = tid & 63;
    int mrow = lane & 15;
    int q8 = (lane >> 4) * 8;
    int pb = blockIdx.x * PXT;
    int bimg = pb >> 12;

    // preamble 1: per-pixel cumulative offsets (6 values)
    if (tid < PXT * 6) {
        int px = tid / 6, s = tid - px * 6;
        int m = pb + px;
        int chn = (s < 3) ? s * 6 : (s - 3) * 2 + 1;
        float v = b_off[chn];
        #pragma unroll
        for (int q = 0; q < 4; ++q) v += partial[((size_t)(q << 15) + m) * 6 + s];
        offs[tid] = v;
    }
    __syncthreads();
    // preamble 2: sample coords gxy[px][k]
    for (int idx = tid; idx < PXT * 9; idx += 256) {
        int px = idx / 9, k = idx - px * 9;
        int i = k / 3, j = k - i * 3;
        float ox = offs[px * 6 + 0];
        if (i >= 1) ox += offs[px * 6 + 1];
        if (i >= 2) ox += offs[px * 6 + 2];
        float oy = offs[px * 6 + 3];
        if (j >= 1) oy += offs[px * 6 + 4];
        if (j >= 2) oy += offs[px * 6 + 5];
        int m = pb + px;
        int h = (m & 4095) >> 6;
        int w = m & 63;
        const float step = 2.0f / 63.0f;
        float bxn = -1.0f + w * step;
        float byn = -1.0f + h * step;
        gxy[idx] = make_float2(fmaf(bxn + ox, 32.0f, 31.5f),
                               fmaf(byn + oy, 32.0f, 31.5f));
    }
    __syncthreads();

    int spx = tid >> 3;          // 0..31
    int scg = tid & 7;           // 0..7
    const u32* xb = (const u32*)(xt + (((size_t)bimg << 12) * CH));

    // prologue: sample step 0 into buffer 0
    {
        uint4 v = sample8(xb, gxy[spx * 9 + 0], scg * 8);
        *(uint4*)&lB[0][spx * LDB + scg * 8] = v;
    }
    __syncthreads();

    float4v acc[2][2];
    #pragma unroll
    for (int sm = 0; sm < 2; ++sm)
        #pragma unroll
        for (int sn = 0; sn < 2; ++sn)
            acc[sm][sn] = (float4v){0.f, 0.f, 0.f, 0.f};

    const u16* Wrow = Wb + (size_t)(wave * 32 + mrow) * KD;   // this lane's A row (sm=0)

    for (int ks = 0; ks < 18; ++ks) {
        int buf = ks & 1;
        int cbase = (ks >> 1) * 128 + (ks & 1) * 64;
        // A fragments: direct global (L2-hit) loads
        short8 af[2][2];
        #pragma unroll
        for (int sm = 0; sm < 2; ++sm)
            #pragma unroll
            for (int s = 0; s < 2; ++s)
                af[sm][s] = *(const short8*)(Wrow + (size_t)sm * 16 * KD + cbase + s * 32 + q8);
        // sample next step into the other buffer
        int ksn = ks + 1;
        if (ksn < 18) {
            int k2 = ksn >> 1, ch2 = ksn & 1;
            uint4 v = sample8(xb, gxy[spx * 9 + k2], ch2 * 64 + scg * 8);
            *(uint4*)&lB[buf ^ 1][spx * LDB + scg * 8] = v;
        }
        // MFMA on current buffer
        #pragma unroll
        for (int s = 0; s < 2; ++s) {
            short8 bfv[2];
            #pragma unroll
            for (int sn = 0; sn < 2; ++sn)
                bfv[sn] = *(const short8*)&lB[buf][(sn * 16 + mrow) * LDB + s * 32 + q8];
            #pragma unroll
            for (int sm = 0; sm < 2; ++sm)
                #pragma unroll
                for (int sn = 0; sn < 2; ++sn)
                    acc[sm][sn] = __builtin_amdgcn_mfma_f32_16x16x32_bf16(af[sm][s], bfv[sn],
                                                                         acc[sm][sn], 0, 0, 0);
        }
        __syncthreads();
    }

    // epilogue: C/D layout col=lane&15 (pixel), row=(lane>>4)*4+r (o)
    #pragma unroll
    for (int sm = 0; sm < 2; ++sm) {
        int o = wave * 32 + sm * 16 + (lane >> 4) * 4;
        #pragma unroll
        for (int sn = 0; sn < 2; ++sn) {
            int pcol = pb + sn * 16 + mrow;
            int rem = pcol & 4095;
            float* op = out + (((size_t)bimg * OO) << 12) + rem;
            #pragma unroll
            for (int r = 0; r < 4; ++r)
                op[(size_t)(o + r) << 12] = acc[sm][sn][r] + b_main[o + r];
        }
    }
}

extern "C" void kernel_launch(void* const* d_in, const int* in_sizes, int n_in,
                              void* d_out, int out_size, void* d_ws, size_t ws_size,
                              hipStream_t stream) {
    const float* x      = (const float*)d_in[0];
    const float* w_off  = (const float*)d_in[1];
    const float* b_off  = (const float*)d_in[2];
    const float* w_main = (const float*)d_in[3];
    const float* b_main = (const float*)d_in[4];
    float* out = (float*)d_out;

    char* ws = (char*)d_ws;
    __hip_bfloat16* xt = (__hip_bfloat16*)ws;                         // 8 MB
    float* partial = (float*)(ws + 8388608);                          // 3 MB
    u16* Wb   = (u16*)(ws + 8388608 + 3145728);                       // 288 KB

    prep_kernel<<<1600, 256, 0, stream>>>(x, w_off, w_main, xt, partial, Wb);
    fused_gemm_kernel<<<1024, 256, 0, stream>>>(xt, partial, b_off, Wb, b_main, out);
}

// Round 5
// 141.102 us; speedup vs baseline: 1.2162x; 1.0171x over previous
//
#include <hip/hip_runtime.h>
#include <hip/hip_bf16.h>
#include <stdint.h>

typedef unsigned short u16;
typedef unsigned int u32;
typedef __attribute__((ext_vector_type(8))) short short8;
typedef __attribute__((ext_vector_type(4))) float float4v;

#define CH 128
#define OO 128
#define KD 1152      // 9*128

__device__ __forceinline__ u16 f2bf(float v) {
    __hip_bfloat16 h = __float2bfloat16(v);
    return *reinterpret_cast<u16*>(&h);
}
__device__ __forceinline__ float bf_lo(u32 u) { u32 t = u << 16;         return __builtin_bit_cast(float, t); }
__device__ __forceinline__ float bf_hi(u32 u) { u32 t = u & 0xffff0000u; return __builtin_bit_cast(float, t); }
__device__ __forceinline__ u32 pack_bf16(float lo, float hi) {
    u32 ul = __builtin_bit_cast(u32, lo);
    u32 uh = __builtin_bit_cast(u32, hi);
    return ((ul + 0x8000u) >> 16) | ((uh + 0x8000u) & 0xffff0000u);
}

// ---------------- prep: transpose (bid<512) | offset conv (512..1023) | w-swizzle (1024..1095) ----
__global__ __launch_bounds__(256) void prep_kernel(const float* __restrict__ x,
                                                   const float* __restrict__ w_off,
                                                   const float* __restrict__ w_main,
                                                   __hip_bfloat16* __restrict__ xt,
                                                   float* __restrict__ partial,
                                                   u16* __restrict__ WbSwz) {
    __shared__ float st[64][65];
    int bid = blockIdx.x;
    int tid = threadIdx.x;
    if (bid < 512) {
        // transpose x (B,C,H,W) f32 -> xt (B,H,W,C) bf16
        int b = bid >> 6;
        int h = bid & 63;
        const float* xb = x + ((size_t)b * CH) * 4096 + (size_t)h * 64;
        __hip_bfloat16* xo = xt + ((size_t)bid << 6) * CH;
        for (int cc0 = 0; cc0 < 128; cc0 += 64) {
            #pragma unroll
            for (int step = 0; step < 16; ++step) {
                int cl = (tid >> 6) + step * 4;
                int w = tid & 63;
                st[cl][w] = xb[(size_t)(cc0 + cl) * 4096 + w];
            }
            __syncthreads();
            #pragma unroll
            for (int step = 0; step < 16; ++step) {
                int w = (tid >> 6) + step * 4;
                int cl = tid & 63;
                xo[(size_t)w * CH + cc0 + cl] = __float2bfloat16(st[cl][w]);
            }
            __syncthreads();
        }
    } else if (bid < 1024) {
        // offset conv: only the 6 needed channels, 4-way c-split
        int mb = (bid - 512) & 127;
        int chunk = (bid - 512) >> 7;
        int m = mb * 256 + tid;
        int b = m >> 12;
        int hw = m & 4095;
        int h = hw >> 6;
        int w = hw & 63;
        float acc[6] = {0.f, 0.f, 0.f, 0.f, 0.f, 0.f};
        int c0 = chunk * 32;
        for (int c = c0; c < c0 + 32; ++c) {
            const float* xc = x + ((size_t)(b * CH + c) << 12);
            float xv[9];
            #pragma unroll
            for (int dy = 0; dy < 3; ++dy) {
                int yy = h + dy - 1;
                bool vy = (unsigned)yy < 64u;
                #pragma unroll
                for (int dx = 0; dx < 3; ++dx) {
                    int xx = w + dx - 1;
                    bool vv = vy && ((unsigned)xx < 64u);
                    xv[dy * 3 + dx] = vv ? xc[yy * 64 + xx] : 0.f;
                }
            }
            const float* wbp = w_off + (size_t)c * 9;
            #pragma unroll
            for (int s = 0; s < 6; ++s) {
                int chn = (s < 3) ? s * 6 : (s - 3) * 2 + 1;
                const float* wp = wbp + (size_t)chn * (CH * 9);
                float a = acc[s];
                #pragma unroll
                for (int t = 0; t < 9; ++t) a = fmaf(xv[t], wp[t], a);
                acc[s] = a;
            }
        }
        float* po = partial + ((size_t)(chunk << 15) + m) * 6;
        #pragma unroll
        for (int s = 0; s < 6; ++s) po[s] = acc[s];
    } else {
        // w_main (O,C,3,3) f32 -> WbSwz: per (kc,t,lane) an 8-u16 A-fragment.
        // A[m][k]: m = t*16 + (lane&15), k = kc*32 + (lane>>4)*8 + j; k -> (tap=k>>7, c=k&127)
        int unit = (bid - 1024) * 256 + tid;      // 0..18431
        int lane6 = unit & 63;
        int t = (unit >> 6) & 7;
        int kc = unit >> 9;
        int o = t * 16 + (lane6 & 15);
        int q8 = (lane6 >> 4) * 8;
        int tap = kc >> 2;
        int cb = (kc & 3) * 32 + q8;
        u16 v8[8];
        #pragma unroll
        for (int j = 0; j < 8; ++j)
            v8[j] = f2bf(w_main[(size_t)o * KD + (cb + j) * 9 + tap]);
        *(uint4*)(WbSwz + (size_t)unit * 8) = *(const uint4*)v8;
    }
}

// ---------------- fused deformable-sample + GEMM v3 ----------------
// 4 waves/block, 16 pixels/wave (B-fragments sampled straight into registers:
// lane's B-frag = 8 channels of pixel lane&15 -- no LDS for B, no barrier on B path).
// A staged per-tap (32 KB) into LDS in swizzled per-lane-fragment order.
__global__ __launch_bounds__(256, 2) void fused_gemm_kernel(const __hip_bfloat16* __restrict__ xt,
                                                            const float* __restrict__ partial,
                                                            const float* __restrict__ b_off,
                                                            const u16* __restrict__ WbSwz,
                                                            const float* __restrict__ b_main,
                                                            float* __restrict__ out) {
    __shared__ __align__(16) u16 lA[16384];       // one tap: 4 chunks x 8 KB = 32 KB

    int tid = threadIdx.x;
    int wave = tid >> 6;
    int lane = tid & 63;
    int col = lane & 15;                          // pixel-in-tile = MFMA col
    int q8 = (lane >> 4) * 8;                     // k-subgroup
    int pbw = blockIdx.x * 64 + wave * 16;        // this wave's pixel base
    int m = pbw + col;                            // this lane's pixel
    int bimg = m >> 12;
    int h = (m & 4095) >> 6;
    int w = m & 63;

    // ---- per-lane preamble: offsets -> sample coords gx[3](i), gy[3](j) ----
    float o6[6];
    #pragma unroll
    for (int s = 0; s < 6; ++s) {
        int chn = (s < 3) ? s * 6 : (s - 3) * 2 + 1;
        float v = b_off[chn];
        #pragma unroll
        for (int q = 0; q < 4; ++q) v += partial[((size_t)(q << 15) + m) * 6 + s];
        o6[s] = v;
    }
    float ox0 = o6[0], ox1 = ox0 + o6[1], ox2 = ox1 + o6[2];
    float oy0 = o6[3], oy1 = oy0 + o6[4], oy2 = oy1 + o6[5];
    const float step = 2.0f / 63.0f;
    float bxn = -1.0f + w * step;
    float byn = -1.0f + h * step;
    float gx0 = fmaf(bxn + ox0, 32.0f, 31.5f);
    float gx1 = fmaf(bxn + ox1, 32.0f, 31.5f);
    float gx2 = fmaf(bxn + ox2, 32.0f, 31.5f);
    float gy0 = fmaf(byn + oy0, 32.0f, 31.5f);
    float gy1 = fmaf(byn + oy1, 32.0f, 31.5f);
    float gy2 = fmaf(byn + oy2, 32.0f, 31.5f);

    const u32* xb = (const u32*)(xt + (((size_t)bimg << 12) * CH));   // bf16 pairs

    float4v acc[8];
    #pragma unroll
    for (int t = 0; t < 8; ++t) acc[t] = (float4v){0.f, 0.f, 0.f, 0.f};

    for (int tap = 0; tap < 9; ++tap) {
        // ---- stage this tap's A slice (32 KB, linear, coalesced) ----
        __syncthreads();
        const uint4* s4 = (const uint4*)(WbSwz + (size_t)tap * 16384);
        uint4* d4 = (uint4*)lA;
        #pragma unroll
        for (int it = 0; it < 8; ++it) d4[it * 256 + tid] = s4[it * 256 + tid];
        __syncthreads();

        // ---- per-tap hoisted bilinear quantities (uniform over the 4 sub-chunks) ----
        float gxi = (tap >= 6) ? gx2 : ((tap >= 3) ? gx1 : gx0);   // i = tap/3
        int jm = tap - ((tap >= 6) ? 6 : ((tap >= 3) ? 3 : 0));    // j = tap%3
        float gyj = (jm == 2) ? gy2 : ((jm == 1) ? gy1 : gy0);
        float x0f = floorf(gxi), y0f = floorf(gyj);
        float wx = gxi - x0f, wy = gyj - y0f;
        int ix0 = (int)x0f, iy0 = (int)y0f;
        int ix1 = ix0 + 1, iy1 = iy0 + 1;
        float fx0 = ((unsigned)ix0 < 64u) ? 1.f : 0.f;
        float fx1 = ((unsigned)ix1 < 64u) ? 1.f : 0.f;
        float fy0 = ((unsigned)iy0 < 64u) ? 1.f : 0.f;
        float fy1 = ((unsigned)iy1 < 64u) ? 1.f : 0.f;
        float w00 = (1.f - wy) * (1.f - wx) * fy0 * fx0;
        float w01 = (1.f - wy) * wx * fy0 * fx1;
        float w10 = wy * (1.f - wx) * fy1 * fx0;
        float w11 = wy * wx * fy1 * fx1;
        int cx0 = min(max(ix0, 0), 63), cx1 = min(max(ix1, 0), 63);
        int cy0 = min(max(iy0, 0), 63), cy1 = min(max(iy1, 0), 63);
        int r00 = (cy0 * 64 + cx0) * CH + q8;     // u16 index of this lane's 8-ch group, c-offset added per sub-chunk
        int r01 = (cy0 * 64 + cx1) * CH + q8;
        int r10 = (cy1 * 64 + cx0) * CH + q8;
        int r11 = (cy1 * 64 + cx1) * CH + q8;

        #pragma unroll
        for (int cc = 0; cc < 4; ++cc) {          // sub-chunk: channels cc*32 + q8 .. +8
            int co = cc * 16;                     // u32 offset (32 ch / 2)
            uint4 u00 = *(const uint4*)(xb + (r00 >> 1) + co);
            uint4 u01 = *(const uint4*)(xb + (r01 >> 1) + co);
            uint4 u10 = *(const uint4*)(xb + (r10 >> 1) + co);
            uint4 u11 = *(const uint4*)(xb + (r11 >> 1) + co);
            const u32* p00 = (const u32*)&u00;
            const u32* p01 = (const u32*)&u01;
            const u32* p10 = (const u32*)&u10;
            const u32* p11 = (const u32*)&u11;
            u32 bp[4];
            #pragma unroll
            for (int qq = 0; qq < 4; ++qq) {
                float lo = w00 * bf_lo(p00[qq]);
                lo = fmaf(w01, bf_lo(p01[qq]), lo);
                lo = fmaf(w10, bf_lo(p10[qq]), lo);
                lo = fmaf(w11, bf_lo(p11[qq]), lo);
                float hi = w00 * bf_hi(p00[qq]);
                hi = fmaf(w01, bf_hi(p01[qq]), hi);
                hi = fmaf(w10, bf_hi(p10[qq]), hi);
                hi = fmaf(w11, bf_hi(p11[qq]), hi);
                bp[qq] = pack_bf16(lo, hi);
            }
            short8 bfrag = *(const short8*)bp;
            #pragma unroll
            for (int t = 0; t < 8; ++t) {
                short8 af = *(const short8*)&lA[((cc * 8 + t) * 64 + lane) * 8];
                acc[t] = __builtin_amdgcn_mfma_f32_16x16x32_bf16(af, bfrag, acc[t], 0, 0, 0);
            }
        }
    }

    // ---- epilogue: C/D layout col=lane&15 (pixel), row=(lane>>4)*4+r (o) ----
    int quad4 = (lane >> 4) * 4;
    int rem = m & 4095;
    #pragma unroll
    for (int t = 0; t < 8; ++t) {
        int ob = t * 16 + quad4;
        float4 bm = *(const float4*)(b_main + ob);
        float* op = out + (((size_t)(bimg * OO + ob)) << 12) + rem;
        op[0] = acc[t][0] + bm.x;
        op[4096] = acc[t][1] + bm.y;
        op[8192] = acc[t][2] + bm.z;
        op[12288] = acc[t][3] + bm.w;
    }
}

extern "C" void kernel_launch(void* const* d_in, const int* in_sizes, int n_in,
                              void* d_out, int out_size, void* d_ws, size_t ws_size,
                              hipStream_t stream) {
    const float* x      = (const float*)d_in[0];
    const float* w_off  = (const float*)d_in[1];
    const float* b_off  = (const float*)d_in[2];
    const float* w_main = (const float*)d_in[3];
    const float* b_main = (const float*)d_in[4];
    float* out = (float*)d_out;

    char* ws = (char*)d_ws;
    __hip_bfloat16* xt = (__hip_bfloat16*)ws;                         // 8 MB
    float* partial = (float*)(ws + 8388608);                          // 3 MB
    u16* WbSwz = (u16*)(ws + 8388608 + 3145728);                      // 288 KB

    prep_kernel<<<1096, 256, 0, stream>>>(x, w_off, w_main, xt, partial, WbSwz);
    fused_gemm_kernel<<<512, 256, 0, stream>>>(xt, partial, b_off, WbSwz, b_main, out);
}